// Round 5
// baseline (98.615 us; speedup 1.0000x reference)
//
#include <hip/hip_runtime.h>
#include <hip/hip_bf16.h>

#define N 8192
#define D 128
#define T64 64
#define NT64 (N / T64)                 // 128 tile-rows of 64
#define NPAIR (NT64 * (NT64 + 1) / 2)  // 8256 upper-tri pairs = 64*5 + 1984*4

typedef __attribute__((ext_vector_type(8))) short short8;
typedef __attribute__((ext_vector_type(4))) float floatx4;
typedef unsigned int u32;

static __device__ inline float softplus_of(const float* __restrict__ phi) {
    float p = phi[0];
    return (p > 20.f) ? p : log1pf(__expf(p));
}

static __device__ inline unsigned short f2bf(float f) {
    return __builtin_bit_cast(unsigned short, __float2bfloat16(f));
}

static __device__ inline short8 pack8(float4 a, float4 b) {
    short8 r;
    r[0] = (short)f2bf(a.x); r[1] = (short)f2bf(a.y);
    r[2] = (short)f2bf(a.z); r[3] = (short)f2bf(a.w);
    r[4] = (short)f2bf(b.x); r[5] = (short)f2bf(b.y);
    r[6] = (short)f2bf(b.z); r[7] = (short)f2bf(b.w);
    return r;
}

// k1: FUSED prep — out = x + var*noise (the former k4), bf16x (XOR-swizzled
// 16B groups), sq[r] = ||bf16(x_r)||^2, rowsum zero-init.
// One thread per 16B group: N*16/256 = 512 blocks.
__global__ __launch_bounds__(256) void k1_prep(
        const float* __restrict__ x, const float* __restrict__ phi,
        const float* __restrict__ noise, float* __restrict__ out,
        unsigned short* __restrict__ bf16x, float* __restrict__ sq,
        float* __restrict__ rowsum) {
    int gid = blockIdx.x * 256 + threadIdx.x;
    int row = gid >> 4;
    int gc  = gid & 15;
    float var = softplus_of(phi);

    const float* xs = x     + (size_t)row * D + gc * 8;
    const float* ns = noise + (size_t)row * D + gc * 8;
    float4 u  = *(const float4*)xs, v  = *(const float4*)(xs + 4);
    float4 nu = *(const float4*)ns, nv = *(const float4*)(ns + 4);

    float4 o0, o1;
    o0.x = u.x + var * nu.x; o0.y = u.y + var * nu.y;
    o0.z = u.z + var * nu.z; o0.w = u.w + var * nu.w;
    o1.x = v.x + var * nv.x; o1.y = v.y + var * nv.y;
    o1.z = v.z + var * nv.z; o1.w = v.w + var * nv.w;
    float* od = out + (size_t)row * D + gc * 8;
    *(float4*)od = o0; *(float4*)(od + 4) = o1;

    short8 p = pack8(u, v);
    *(short8*)&bf16x[(size_t)row * D + (size_t)(gc ^ (row & 15)) * 8] = p;

    float s = 0.f;
    #pragma unroll
    for (int k = 0; k < 8; k++) {
        u32 bits = ((u32)(unsigned short)p[k]) << 16;
        float b = __builtin_bit_cast(float, bits);
        s += b * b;
    }
    #pragma unroll
    for (int m = 1; m < 16; m <<= 1) s += __shfl_xor(s, m, 64);
    if (gc == 0) { sq[row] = s; rowsum[row] = 0.f; }
}

// k2: barrier-free symmetric Gram. 2048 independent waves; wave w owns 4
// (5 for w<64) consecutive upper-tri 64x64 tile-pairs (ti<=tj). A- and
// B-fragments live entirely in registers (B loaded straight from the
// L2-resident bf16x; next pair's B issued during the current exp epilogue).
// Row-sums of ti accumulate in registers (flushed on ti change); column
// sums -> rows of tj via symmetry, flushed per pair. No LDS, no barriers.
__global__ __launch_bounds__(256, 2) void k2_gram(
        const unsigned short* __restrict__ bf16x, const float* __restrict__ phi,
        const float* __restrict__ sq, float* __restrict__ rowsum) {
    const int w    = blockIdx.x * 4 + (threadIdx.x >> 6);
    const int lane = threadIdx.x & 63;
    const int lrow = lane & 15;
    const int quad = lane >> 4;

    const int cnt = (w < 64) ? 5 : 4;
    int start     = (w < 64) ? 5 * w : 4 * w + 64;
    int ti = 0, rem = start, len = NT64;
    while (rem >= len) { rem -= len; ++ti; --len; }
    int tj = ti + rem;

    float var = softplus_of(phi);
    const float e2c = (-0.5f / var) * 1.4426950408889634f;  // ln->log2 folded
    const float m2c = -2.0f * e2c;

    short8 af[4][4], bf[4][4];
    float  sie[4][4], rowAcc[4][4];
    int curTi = -1;

    // prologue: B fragments for the first pair
    {
        const unsigned short* bb = bf16x + (size_t)tj * T64 * D;
        #pragma unroll
        for (int nt = 0; nt < 4; nt++) {
            const unsigned short* br = bb + (size_t)(nt * 16 + lrow) * D;
            #pragma unroll
            for (int kk = 0; kk < 4; kk++)
                bf[nt][kk] = *(const short8*)&br[((kk * 4 + quad) ^ lrow) * 8];
        }
    }

    for (int r = 0; r < cnt; ++r) {
        const int iB = ti * T64, jB = tj * T64;

        float sje[4];
        #pragma unroll
        for (int nt = 0; nt < 4; nt++)
            sje[nt] = sq[jB + nt * 16 + lrow] * e2c;

        if (ti != curTi) {
            if (curTi >= 0) {  // flush previous ti's row sums
                const int pB = curTi * T64;
                #pragma unroll
                for (int mt = 0; mt < 4; mt++)
                    #pragma unroll
                    for (int reg = 0; reg < 4; reg++) {
                        float vv = rowAcc[mt][reg];
                        #pragma unroll
                        for (int m = 1; m < 16; m <<= 1) vv += __shfl_xor(vv, m, 64);
                        if (lrow == 0)
                            atomicAdd(&rowsum[pB + mt * 16 + quad * 4 + reg], vv);
                    }
            }
            #pragma unroll
            for (int mt = 0; mt < 4; mt++) {
                const unsigned short* ar = bf16x + (size_t)(iB + mt * 16 + lrow) * D;
                #pragma unroll
                for (int kk = 0; kk < 4; kk++)
                    af[mt][kk] = *(const short8*)&ar[((kk * 4 + quad) ^ lrow) * 8];
            }
            #pragma unroll
            for (int mt = 0; mt < 4; mt++)
                #pragma unroll
                for (int reg = 0; reg < 4; reg++) {
                    sie[mt][reg] = sq[iB + mt * 16 + quad * 4 + reg] * e2c;
                    rowAcc[mt][reg] = 0.f;
                }
            curTi = ti;
        }

        int nti = ti, ntj = tj + 1;
        if (ntj == NT64) { ++nti; ntj = nti; }

        float colAcc[4] = {0.f, 0.f, 0.f, 0.f};
        #pragma unroll
        for (int nt = 0; nt < 4; nt++) {
            // MFMA for this nt-column (acc liveness kept at 16 VGPRs)
            floatx4 acc[4] = {};
            #pragma unroll
            for (int kk = 0; kk < 4; kk++)
                #pragma unroll
                for (int mt = 0; mt < 4; mt++)
                    acc[mt] = __builtin_amdgcn_mfma_f32_16x16x32_bf16(
                        af[mt][kk], bf[nt][kk], acc[mt], 0, 0, 0);

            // after the last nt consumed bf: issue next pair's B loads; they
            // land during the remaining epilogue (~no barrier ever drains them)
            if (nt == 3 && r + 1 < cnt) {
                const unsigned short* bb = bf16x + (size_t)ntj * T64 * D;
                #pragma unroll
                for (int n2 = 0; n2 < 4; n2++) {
                    const unsigned short* br = bb + (size_t)(n2 * 16 + lrow) * D;
                    #pragma unroll
                    for (int kk = 0; kk < 4; kk++)
                        bf[n2][kk] = *(const short8*)&br[((kk * 4 + quad) ^ lrow) * 8];
                }
            }

            // epilogue: p = exp2(min(si*c + sj*c - 2c*g, 0)); row & col sums
            // C/D layout: col = lane&15, row = quad*4 + reg   [learn_hip m89]
            float sj = sje[nt];
            #pragma unroll
            for (int mt = 0; mt < 4; mt++)
                #pragma unroll
                for (int reg = 0; reg < 4; reg++) {
                    float p2 = fminf(fmaf(acc[mt][reg], m2c, sie[mt][reg] + sj), 0.f);
                    float p  = __builtin_amdgcn_exp2f(p2);
                    rowAcc[mt][reg] += p;
                    colAcc[nt]      += p;
                }
        }

        if (ti != tj) {  // strictly-upper: column sums -> rows of tj
            #pragma unroll
            for (int nt = 0; nt < 4; nt++) {
                float vv = colAcc[nt];
                vv += __shfl_xor(vv, 16, 64);
                vv += __shfl_xor(vv, 32, 64);
                if (quad == 0)
                    atomicAdd(&rowsum[jB + nt * 16 + lrow], vv);
            }
        }

        ti = nti; tj = ntj;
    }

    // final row flush
    {
        const int pB = curTi * T64;
        #pragma unroll
        for (int mt = 0; mt < 4; mt++)
            #pragma unroll
            for (int reg = 0; reg < 4; reg++) {
                float vv = rowAcc[mt][reg];
                #pragma unroll
                for (int m = 1; m < 16; m <<= 1) vv += __shfl_xor(vv, m, 64);
                if (lrow == 0)
                    atomicAdd(&rowsum[pB + mt * 16 + quad * 4 + reg], vv);
            }
    }
}

// k3: IXT = (ln N - mean_i ln rowsum[i]) / ln 2
__global__ __launch_bounds__(1024) void k3_final(
        const float* __restrict__ rowsum, float* __restrict__ out_ixt) {
    __shared__ float red[16];
    int t = threadIdx.x;
    float local = 0.f;
    for (int i = t; i < N; i += 1024) local += logf(rowsum[i]);
    #pragma unroll
    for (int m = 1; m < 64; m <<= 1) local += __shfl_xor(local, m, 64);
    if ((t & 63) == 0) red[t >> 6] = local;
    __syncthreads();
    if (t < 16) {
        float v = red[t];
        #pragma unroll
        for (int m = 1; m < 16; m <<= 1) v += __shfl_xor(v, m, 64);
        if (t == 0) {
            float kde = v / (float)N;
            out_ixt[0] = (logf((float)N) - kde) * 1.4426950408889634f;
        }
    }
}

extern "C" void kernel_launch(void* const* d_in, const int* in_sizes, int n_in,
                              void* d_out, int out_size, void* d_ws, size_t ws_size,
                              hipStream_t stream) {
    const float* x     = (const float*)d_in[0];
    const float* phi   = (const float*)d_in[1];
    const float* noise = (const float*)d_in[2];
    float* out = (float*)d_out;

    // d_ws layout (ws is ~268 MB per harness fill evidence; we use ~2.1 MB):
    float* rowsum = (float*)d_ws;                         // N floats
    float* sq     = rowsum + N;                           // N floats
    unsigned short* bf16x = (unsigned short*)(sq + N);    // N*D bf16 = 2 MB

    k1_prep<<<(N * 16) / 256, 256, 0, stream>>>(x, phi, noise, out, bf16x, sq, rowsum);
    k2_gram<<<512, 256, 0, stream>>>(bf16x, phi, sq, rowsum);
    k3_final<<<1, 1024, 0, stream>>>(rowsum, out + (size_t)N * D);
}